// Round 7
// baseline (425.567 us; speedup 1.0000x reference)
//
#include <hip/hip_runtime.h>
#include <hip/hip_bf16.h>
#include <math.h>

// MAGNN link prediction forward — fp32 compute; feat table stored bf16.
#define NN0 20000
#define NN1 20000
#define NTOT 40000
#define FF0 512
#define HIDD 64
#define EEE 200000
#define BBB 8192
#define AVV 128
#define CHH 128

__device__ __forceinline__ float fast_tanh(float x) {
    float e2 = __expf(2.f * x);
    return 1.f - 2.f / (e2 + 1.f);
}

// ---------------- tower: Linear(512->64) + GELU + Linear(64->64) + residual + LN ----------------
// 64-row tiles, 256 threads, 4x4 register tile; K-loop register-double-buffered:
// store staged regs->LDS, barrier, issue NEXT chunk's global loads, compute current.
__global__ __launch_bounds__(256) void tower_kernel(
    const float* __restrict__ x0, const float* __restrict__ x1,
    const float* __restrict__ pw0, const float* __restrict__ pw1,
    const float* __restrict__ pb0, const float* __restrict__ pb1,
    const float* __restrict__ w20, const float* __restrict__ w21,
    const float* __restrict__ b20, const float* __restrict__ b21,
    const float* __restrict__ g0, const float* __restrict__ g1,
    const float* __restrict__ be0, const float* __restrict__ be1,
    const int* __restrict__ idxa, const int* __restrict__ idxb,
    __hip_bfloat16* __restrict__ feat)
{
    int tw = blockIdx.y;
    const float* x  = tw ? x1 : x0;
    const float* pw = tw ? pw1 : pw0;
    const float* pb = tw ? pb1 : pb0;
    const float* w2 = tw ? w21 : w20;
    const float* b2 = tw ? b21 : b20;
    const float* g  = tw ? g1 : g0;
    const float* be = tw ? be1 : be0;
    const int* idx  = tw ? idxb : idxa;
    int nrows = NN0;

    __shared__ float xs[64][68];   // x k-chunk; reused for gelu(h), then y (barrier-sequenced)
    __shared__ float wsh[64][64];  // pw chunk, then w2
    int tid = threadIdx.x;
    int ct = tid & 15, rt = tid >> 4;
    int row0 = blockIdx.x * 64;

    // register staging buffers (4 float4 each: 1024 float4 / 256 threads)
    float4 xreg[4], wreg[4];
    int lr[4], lk4[4];
#pragma unroll
    for (int q = 0; q < 4; q++) {
        int li = tid + q * 256;
        lr[q] = li >> 4; lk4[q] = (li & 15) * 4;
    }

    // prologue: load chunk 0
#pragma unroll
    for (int q = 0; q < 4; q++) {
        int gr = row0 + lr[q];
        xreg[q] = (gr < nrows) ? *(const float4*)&x[(long)gr * FF0 + 0 + lk4[q]]
                               : make_float4(0.f, 0.f, 0.f, 0.f);
        wreg[q] = ((const float4*)(pw))[tid + q * 256];
    }

    float acc[4][4];
#pragma unroll
    for (int j = 0; j < 4; j++)
#pragma unroll
        for (int i = 0; i < 4; i++) acc[j][i] = 0.f;

    for (int chunk = 0; chunk < 8; chunk++) {
        if (chunk > 0) __syncthreads();   // prev compute done before overwriting LDS
#pragma unroll
        for (int q = 0; q < 4; q++) {
            *(float4*)&xs[lr[q]][lk4[q]] = xreg[q];
            *(float4*)&wsh[lr[q]][lk4[q]] = wreg[q];
        }
        __syncthreads();
        // issue next chunk's loads (latency hidden by compute below)
        if (chunk < 7) {
            int k0 = (chunk + 1) * 64;
#pragma unroll
            for (int q = 0; q < 4; q++) {
                int gr = row0 + lr[q];
                xreg[q] = (gr < nrows) ? *(const float4*)&x[(long)gr * FF0 + k0 + lk4[q]]
                                       : make_float4(0.f, 0.f, 0.f, 0.f);
                wreg[q] = ((const float4*)(pw + k0 * 64))[tid + q * 256];
            }
        } else {
            // prefetch w2 for GEMM2
#pragma unroll
            for (int q = 0; q < 4; q++) wreg[q] = ((const float4*)w2)[tid + q * 256];
        }
        // compute current chunk
        for (int k = 0; k < 64; k += 4) {
            float4 xv[4];
#pragma unroll
            for (int j = 0; j < 4; j++) xv[j] = *(const float4*)&xs[4 * rt + j][k];
#pragma unroll
            for (int kk = 0; kk < 4; kk++) {
                float4 wv = *(const float4*)&wsh[k + kk][4 * ct];
#pragma unroll
                for (int j = 0; j < 4; j++) {
                    float xx = kk == 0 ? xv[j].x : kk == 1 ? xv[j].y : kk == 2 ? xv[j].z : xv[j].w;
                    acc[j][0] = fmaf(xx, wv.x, acc[j][0]);
                    acc[j][1] = fmaf(xx, wv.y, acc[j][1]);
                    acc[j][2] = fmaf(xx, wv.z, acc[j][2]);
                    acc[j][3] = fmaf(xx, wv.w, acc[j][3]);
                }
            }
        }
    }
    __syncthreads();   // all reads of xs/wsh done

    // z = acc + pb; h = gelu(z) -> xs (reused); w2 regs -> wsh
    float4 pbv = *(const float4*)&pb[4 * ct];
    float z[4][4];
#pragma unroll
    for (int j = 0; j < 4; j++) {
        z[j][0] = acc[j][0] + pbv.x; z[j][1] = acc[j][1] + pbv.y;
        z[j][2] = acc[j][2] + pbv.z; z[j][3] = acc[j][3] + pbv.w;
        float4 hv;
        hv.x = 0.5f * z[j][0] * (1.f + erff(z[j][0] * 0.70710678118654752f));
        hv.y = 0.5f * z[j][1] * (1.f + erff(z[j][1] * 0.70710678118654752f));
        hv.z = 0.5f * z[j][2] * (1.f + erff(z[j][2] * 0.70710678118654752f));
        hv.w = 0.5f * z[j][3] * (1.f + erff(z[j][3] * 0.70710678118654752f));
        *(float4*)&xs[4 * rt + j][4 * ct] = hv;
    }
#pragma unroll
    for (int q = 0; q < 4; q++)
        *(float4*)&wsh[lr[q]][lk4[q]] = wreg[q];
    __syncthreads();

    // GEMM2: y = h@w2 + b2 + z
    float4 b2v = *(const float4*)&b2[4 * ct];
    float acc2[4][4];
#pragma unroll
    for (int j = 0; j < 4; j++) {
        acc2[j][0] = z[j][0] + b2v.x; acc2[j][1] = z[j][1] + b2v.y;
        acc2[j][2] = z[j][2] + b2v.z; acc2[j][3] = z[j][3] + b2v.w;
    }
    for (int k = 0; k < 64; k += 4) {
        float4 xv[4];
#pragma unroll
        for (int j = 0; j < 4; j++) xv[j] = *(const float4*)&xs[4 * rt + j][k];
#pragma unroll
        for (int kk = 0; kk < 4; kk++) {
            float4 wv = *(const float4*)&wsh[k + kk][4 * ct];
#pragma unroll
            for (int j = 0; j < 4; j++) {
                float xx = kk == 0 ? xv[j].x : kk == 1 ? xv[j].y : kk == 2 ? xv[j].z : xv[j].w;
                acc2[j][0] = fmaf(xx, wv.x, acc2[j][0]);
                acc2[j][1] = fmaf(xx, wv.y, acc2[j][1]);
                acc2[j][2] = fmaf(xx, wv.z, acc2[j][2]);
                acc2[j][3] = fmaf(xx, wv.w, acc2[j][3]);
            }
        }
    }
    __syncthreads();
#pragma unroll
    for (int j = 0; j < 4; j++)
        *(float4*)&xs[4 * rt + j][4 * ct] = make_float4(acc2[j][0], acc2[j][1], acc2[j][2], acc2[j][3]);
    __syncthreads();

    // LayerNorm: lane = col, 4 waves x 16 rows
    int lane = tid & 63, wid = tid >> 6;
    float gc = g[lane], bec = be[lane];
    for (int rr = wid; rr < 64; rr += 4) {
        float y = xs[rr][lane];
        float mu = y;
        for (int off = 32; off; off >>= 1) mu += __shfl_xor(mu, off);
        mu *= (1.f / 64.f);
        float d = y - mu;
        float var = d * d;
        for (int off = 32; off; off >>= 1) var += __shfl_xor(var, off);
        var *= (1.f / 64.f);
        float o = d / sqrtf(var + 1e-5f) * gc + bec;
        int grow = row0 + rr;
        if (grow < nrows) feat[(long)idx[grow] * HIDD + lane] = __float2bfloat16(o);
    }
}

// ---------------- CSR build: hist -> scan -> binA (coarse) -> binB (exact) ----------------
__global__ void hist_kernel(const int* __restrict__ tgt_user, const int* __restrict__ tgt_item,
                            int* __restrict__ cnt)
{
    int combo = blockIdx.y;
    const int* tgt = (combo < 2 ? tgt_user : tgt_item) + (long)(combo & 1) * EEE;
    int i = blockIdx.x * 256 + threadIdx.x;
    if (i < EEE) atomicAdd(&cnt[combo * BBB + tgt[i]], 1);
}

__global__ __launch_bounds__(256) void scan_kernel(const int* __restrict__ cnt, int* __restrict__ offs,
                                                   int* __restrict__ cur32, float* __restrict__ s_acc)
{
    int pth = blockIdx.x;
    if (pth == 0 && threadIdx.x < 4) s_acc[threadIdx.x] = 0.f;
    const int* c = cnt + pth * BBB;
    int* o = offs + pth * (BBB + 1);
    __shared__ int part[256];
    int tid = threadIdx.x;
    int base = tid * 32;
    int local[32];
    int sum = 0;
    for (int j = 0; j < 32; j++) { local[j] = sum; sum += c[base + j]; }
    part[tid] = sum;
    __syncthreads();
    for (int d = 1; d < 256; d <<= 1) {
        int v = (tid >= d) ? part[tid - d] : 0;
        __syncthreads();
        part[tid] += v;
        __syncthreads();
    }
    int pre = (tid == 0) ? 0 : part[tid - 1];
    for (int j = 0; j < 32; j++) {
        int val = pre + local[j];
        o[base + j] = val;
        if (((base + j) & 255) == 0) cur32[pth * 32 + ((base + j) >> 8)] = val;
    }
    if (tid == 255) o[BBB] = pre + sum;
}

// pass A: bin instances into 32 coarse buckets (256 targets each), LDS-sorted, coalesced run writes
#define CHUNK 2048
__global__ __launch_bounds__(256) void binA_kernel(
    const int* __restrict__ tgt_user, const int* __restrict__ tgt_item,
    const int* __restrict__ emi_user, const int* __restrict__ emi_item,
    int* __restrict__ cur32, ushort4* __restrict__ binbuf)
{
    int combo = blockIdx.y;
    const int* tgt = (combo < 2 ? tgt_user : tgt_item) + (long)(combo & 1) * EEE;
    const int* emi = (combo < 2 ? emi_user : emi_item) + (long)(combo & 1) * EEE * 3;
    __shared__ ushort4 sbuf[CHUNK];
    __shared__ int lcnt[32], lofs[33], gbase[32], lcur[32];
    int tid = threadIdx.x;
    int base = blockIdx.x * CHUNK;
    if (tid < 32) { lcnt[tid] = 0; lcur[tid] = 0; }
    __syncthreads();
    ushort4 ent[8]; int bk[8];
#pragma unroll
    for (int ps = 0; ps < 8; ps++) {
        int i = base + ps * 256 + tid;
        if (i < EEE) {
            int t = tgt[i];
            ent[ps] = make_ushort4((unsigned short)emi[3 * i], (unsigned short)emi[3 * i + 1],
                                   (unsigned short)emi[3 * i + 2], (unsigned short)t);
            bk[ps] = t >> 8;
            atomicAdd(&lcnt[bk[ps]], 1);
        } else bk[ps] = -1;
    }
    __syncthreads();
    if (tid == 0) {
        int run = 0;
        for (int k = 0; k < 32; k++) { lofs[k] = run; run += lcnt[k]; }
        lofs[32] = run;
    }
    __syncthreads();
    if (tid < 32) gbase[tid] = atomicAdd(&cur32[combo * 32 + tid], lcnt[tid]);
    __syncthreads();
#pragma unroll
    for (int ps = 0; ps < 8; ps++) {
        if (bk[ps] >= 0) {
            int pos = lofs[bk[ps]] + atomicAdd(&lcur[bk[ps]], 1);
            sbuf[pos] = ent[ps];
        }
    }
    __syncthreads();
    int total = lofs[32];
    ushort4* dst = binbuf + (long)combo * EEE;
    for (int j = tid; j < total; j += 256) {
        ushort4 e = sbuf[j];
        int k = e.w >> 8;
        dst[gbase[k] + (j - lofs[k])] = e;
    }
}

// pass B: within each coarse bucket (contiguous ~50KB window), place entries at exact CSR position
__global__ __launch_bounds__(256) void binB_kernel(
    const int* __restrict__ offs, int* __restrict__ cur,
    const ushort4* __restrict__ binbuf, ushort4* __restrict__ nodes)
{
    int combo = blockIdx.y;
    int k = blockIdx.x >> 1, part = blockIdx.x & 1;
    const int* of = offs + combo * (BBB + 1);
    int rbeg = of[k << 8], rend = of[(k + 1) << 8];
    const ushort4* src = binbuf + (long)combo * EEE;
    ushort4* dst = nodes + (long)combo * EEE;
    int* cu = cur + combo * BBB;
    for (int j = rbeg + part * 256 + threadIdx.x; j < rend; j += 512) {
        ushort4 e = src[j];
        int t = e.w;
        int pos = of[t] + atomicAdd(&cu[t], 1);
        dst[pos] = e;
    }
}

// ---------------- flash metapath: gather + rotate + attention + online softmax + ELU ----------------
__global__ __launch_bounds__(256) void flash_mp(
    const __hip_bfloat16* __restrict__ feat, const ushort4* __restrict__ nodes,
    const int* __restrict__ offs, const float* __restrict__ r_vec,
    const float* __restrict__ attn_user, const float* __restrict__ attn_item,
    float* __restrict__ ret)
{
    int combo = blockIdx.y;
    int wid = threadIdx.x >> 6, lane = threadIdx.x & 63;
    int half = lane >> 5, p = lane & 31;
    int side = combo >> 1;
    const float* attn = (side == 0 ? attn_user : attn_item) + (combo & 1) * 64;
    const __hip_bfloat162* f2 = (const __hip_bfloat162*)feat;
    float2 rb = ((const float2*)r_vec)[p];
    float invn = 1.f / sqrtf(rb.x * rb.x + rb.y * rb.y);
    float rvx = rb.x * invn, rvy = rb.y * invn;
    if (side == 0) rvy = -rvy;
    float aRe = attn[2 * p], aIm = attn[2 * p + 1];
    int t = blockIdx.x * 4 + wid;
    int beg = offs[combo * (BBB + 1) + t], end = offs[combo * (BBB + 1) + t + 1];
    int n = end - beg;
    const ushort4* nd = nodes + (long)combo * EEE;

    float m = -3.4e38f, s = 0.f, Ox = 0.f, Oy = 0.f;

    __hip_bfloat162 c[8][3];
    ushort4 nq[8];
    if (n > 0) {
#pragma unroll
        for (int q = 0; q < 8; q++) {
            int j = beg + 2 * q + half; if (j >= end) j = end - 1;
            ushort4 a = nd[j];
            c[q][0] = f2[(int)a.x * 32 + p];
            c[q][1] = f2[(int)a.y * 32 + p];
            c[q][2] = f2[(int)a.z * 32 + p];
        }
#pragma unroll
        for (int q = 0; q < 8; q++) {
            int j = beg + 16 + 2 * q + half; if (j >= end) j = end - 1;
            nq[q] = nd[j];
        }
    }
    for (int it = 0; it < n; it += 16) {
        float2 u[8][3];
#pragma unroll
        for (int q = 0; q < 8; q++)
#pragma unroll
            for (int r = 0; r < 3; r++)
                u[q][r] = __bfloat1622float2(c[q][r]);
        if (it + 16 < n) {
#pragma unroll
            for (int q = 0; q < 8; q++) {
                c[q][0] = f2[(int)nq[q].x * 32 + p];
                c[q][1] = f2[(int)nq[q].y * 32 + p];
                c[q][2] = f2[(int)nq[q].z * 32 + p];
            }
#pragma unroll
            for (int q = 0; q < 8; q++) {
                int j = beg + it + 32 + 2 * q + half; if (j >= end) j = end - 1;
                nq[q] = nd[j];
            }
        }
        float re[8], im[8], e[8];
#pragma unroll
        for (int q = 0; q < 8; q++) {
            re[q] = (u[q][0].x + u[q][2].x + u[q][1].x * rvx - u[q][1].y * rvy) * (1.f / 3.f);
            im[q] = (u[q][0].y + u[q][2].y + u[q][1].x * rvy + u[q][1].y * rvx) * (1.f / 3.f);
            float pa = re[q] * aRe + im[q] * aIm;
            pa += __shfl_xor(pa, 1);
            pa += __shfl_xor(pa, 2);
            float ev = pa > 0.f ? pa : 0.01f * pa;       // leaky_relu
            if (it + 2 * q + half >= n) ev = -3.4e38f;
            e[q] = ev;
        }
        float mx = e[0];
#pragma unroll
        for (int q = 1; q < 8; q++) mx = fmaxf(mx, e[q]);
        float mn = fmaxf(m, fmaxf(mx, __shfl_xor(mx, 32)));
        float alpha = __expf(m - mn);
        float wl = 0.f, ax = 0.f, ay = 0.f;
#pragma unroll
        for (int q = 0; q < 8; q++) {
            float w = __expf(e[q] - mn);
            wl += w; ax = fmaf(w, re[q], ax); ay = fmaf(w, im[q], ay);
        }
        s = s * alpha + wl + __shfl_xor(wl, 32);
        Ox = Ox * alpha + ax;
        Oy = Oy * alpha + ay;
        m = mn;
    }
    float sx = __shfl_xor(Ox, 32), sy = __shfl_xor(Oy, 32);
    float inv = 1.f / (s + 1e-9f);
    float vx = (Ox + sx) * inv, vy = (Oy + sy) * inv;
    vx = vx > 0.f ? vx : __expf(vx) - 1.f;   // ELU
    vy = vy > 0.f ? vy : __expf(vy) - 1.f;
    if (half == 0)
        ((float2*)ret)[((long)combo * BBB + t) * 32 + p] = make_float2(vx, vy);
}

// ---------------- semantic score GEMM: s_acc[combo] = sum_b tanh(ret_b @ w1 + b1) @ w2 ----------------
__global__ __launch_bounds__(256) void sem_kernel(
    const float* __restrict__ ret,
    const float* __restrict__ su_w1, const float* __restrict__ su_b1, const float* __restrict__ su_w2,
    const float* __restrict__ si_w1, const float* __restrict__ si_b1, const float* __restrict__ si_w2,
    float* __restrict__ s_acc)
{
    int combo = blockIdx.y;
    int side = combo >> 1;
    const float* w1 = side ? si_w1 : su_w1;
    const float* b1 = side ? si_b1 : su_b1;
    const float* w2 = side ? si_w2 : su_w2;
    __shared__ float vs[64][68];
    __shared__ float w1s[64][128];
    int tid = threadIdx.x;
    int rowbase = blockIdx.x * 64;
    const float4* r4 = (const float4*)ret;
    for (int li = tid; li < 1024; li += 256) {
        int r = li >> 4, c4 = li & 15;
        float4 v = r4[((long)combo * BBB + rowbase + r) * 16 + c4];
        *(float4*)&vs[r][c4 * 4] = v;
    }
    const float4* w14 = (const float4*)w1;
    for (int li = tid; li < 2048; li += 256) {
        float4 v = w14[li];
        *(float4*)&w1s[li >> 5][(li & 31) * 4] = v;
    }
    __syncthreads();
    int ct = tid & 15, rt = tid >> 4;
    float acc[4][8];
#pragma unroll
    for (int cc = 0; cc < 8; cc++) {
        float b = b1[8 * ct + cc];
#pragma unroll
        for (int j = 0; j < 4; j++) acc[j][cc] = b;
    }
    for (int k = 0; k < 64; k += 4) {
        float4 xv[4];
#pragma unroll
        for (int j = 0; j < 4; j++) xv[j] = *(const float4*)&vs[4 * rt + j][k];
#pragma unroll
        for (int kk = 0; kk < 4; kk++) {
            float4 wv0 = *(const float4*)&w1s[k + kk][8 * ct];
            float4 wv1 = *(const float4*)&w1s[k + kk][8 * ct + 4];
#pragma unroll
            for (int j = 0; j < 4; j++) {
                float xx = kk == 0 ? xv[j].x : kk == 1 ? xv[j].y : kk == 2 ? xv[j].z : xv[j].w;
                acc[j][0] = fmaf(xx, wv0.x, acc[j][0]);
                acc[j][1] = fmaf(xx, wv0.y, acc[j][1]);
                acc[j][2] = fmaf(xx, wv0.z, acc[j][2]);
                acc[j][3] = fmaf(xx, wv0.w, acc[j][3]);
                acc[j][4] = fmaf(xx, wv1.x, acc[j][4]);
                acc[j][5] = fmaf(xx, wv1.y, acc[j][5]);
                acc[j][6] = fmaf(xx, wv1.z, acc[j][6]);
                acc[j][7] = fmaf(xx, wv1.w, acc[j][7]);
            }
        }
    }
    float tot = 0.f;
#pragma unroll
    for (int cc = 0; cc < 8; cc++) {
        float w2v = w2[8 * ct + cc];
#pragma unroll
        for (int j = 0; j < 4; j++) tot += fast_tanh(acc[j][cc]) * w2v;
    }
    for (int off = 32; off; off >>= 1) tot += __shfl_xor(tot, off);
    __shared__ float red[4];
    int lane = tid & 63, wid = tid >> 6;
    if (lane == 0) red[wid] = tot;
    __syncthreads();
    if (tid == 0) atomicAdd(&s_acc[combo], red[0] + red[1] + red[2] + red[3]);
}

// ---------------- final product MLP + softmax (beta inline, GEMM-tiled) ----------------
__global__ __launch_bounds__(256) void final_kernel(
    const float* __restrict__ ret, const float* __restrict__ s_acc,
    const float* __restrict__ cw1, const float* __restrict__ cb1, const float* __restrict__ cw2,
    float* __restrict__ outp)
{
    float s0 = s_acc[0] * (1.f / BBB), s1 = s_acc[1] * (1.f / BBB);
    float s2 = s_acc[2] * (1.f / BBB), s3 = s_acc[3] * (1.f / BBB);
    float mu = fmaxf(s0, s1);
    float e0 = __expf(s0 - mu), e1 = __expf(s1 - mu);
    float bu0 = e0 / (e0 + e1), bu1 = e1 / (e0 + e1);
    float mi = fmaxf(s2, s3);
    float f0 = __expf(s2 - mi), f1 = __expf(s3 - mi);
    float bi0 = f0 / (f0 + f1), bi1 = f1 / (f0 + f1);

    __shared__ float xsld[64][68];
    __shared__ float w1s[64][128];
    int tid = threadIdx.x;
    int rowbase = blockIdx.x * 64;
    const float4* r4 = (const float4*)ret;
    for (int li = tid; li < 1024; li += 256) {
        int r = li >> 4, c4 = li & 15;
        float4 a = r4[((long)0 * BBB + rowbase + r) * 16 + c4];
        float4 b = r4[((long)1 * BBB + rowbase + r) * 16 + c4];
        float4 cc = r4[((long)2 * BBB + rowbase + r) * 16 + c4];
        float4 d = r4[((long)3 * BBB + rowbase + r) * 16 + c4];
        float4 xv;
        xv.x = (bu0 * a.x + bu1 * b.x) * (bi0 * cc.x + bi1 * d.x);
        xv.y = (bu0 * a.y + bu1 * b.y) * (bi0 * cc.y + bi1 * d.y);
        xv.z = (bu0 * a.z + bu1 * b.z) * (bi0 * cc.z + bi1 * d.z);
        xv.w = (bu0 * a.w + bu1 * b.w) * (bi0 * cc.w + bi1 * d.w);
        *(float4*)&xsld[r][c4 * 4] = xv;
    }
    const float4* w14 = (const float4*)cw1;
    for (int li = tid; li < 2048; li += 256) {
        float4 v = w14[li];
        *(float4*)&w1s[li >> 5][(li & 31) * 4] = v;
    }
    __syncthreads();
    int ct = tid & 15, rt = tid >> 4;
    float acc[4][8];
#pragma unroll
    for (int cc = 0; cc < 8; cc++) {
        float b = cb1[8 * ct + cc];
#pragma unroll
        for (int j = 0; j < 4; j++) acc[j][cc] = b;
    }
    for (int k = 0; k < 64; k += 4) {
        float4 xv[4];
#pragma unroll
        for (int j = 0; j < 4; j++) xv[j] = *(const float4*)&xsld[4 * rt + j][k];
#pragma unroll
        for (int kk = 0; kk < 4; kk++) {
            float4 wv0 = *(const float4*)&w1s[k + kk][8 * ct];
            float4 wv1 = *(const float4*)&w1s[k + kk][8 * ct + 4];
#pragma unroll
            for (int j = 0; j < 4; j++) {
                float xx = kk == 0 ? xv[j].x : kk == 1 ? xv[j].y : kk == 2 ? xv[j].z : xv[j].w;
                acc[j][0] = fmaf(xx, wv0.x, acc[j][0]);
                acc[j][1] = fmaf(xx, wv0.y, acc[j][1]);
                acc[j][2] = fmaf(xx, wv0.z, acc[j][2]);
                acc[j][3] = fmaf(xx, wv0.w, acc[j][3]);
                acc[j][4] = fmaf(xx, wv1.x, acc[j][4]);
                acc[j][5] = fmaf(xx, wv1.y, acc[j][5]);
                acc[j][6] = fmaf(xx, wv1.z, acc[j][6]);
                acc[j][7] = fmaf(xx, wv1.w, acc[j][7]);
            }
        }
    }
    float pp0[4], pp1[4];
#pragma unroll
    for (int j = 0; j < 4; j++) { pp0[j] = 0.f; pp1[j] = 0.f; }
#pragma unroll
    for (int cc = 0; cc < 8; cc++) {
        int col = 8 * ct + cc;
        float c0 = cw2[col * 2], c1 = cw2[col * 2 + 1];
#pragma unroll
        for (int j = 0; j < 4; j++) {
            float h = fmaxf(acc[j][cc], 0.f);
            pp0[j] = fmaf(h, c0, pp0[j]);
            pp1[j] = fmaf(h, c1, pp1[j]);
        }
    }
    __syncthreads();
    float2* red = (float2*)xsld;
#pragma unroll
    for (int j = 0; j < 4; j++)
        red[(4 * rt + j) * 16 + ct] = make_float2(pp0[j], pp1[j]);
    __syncthreads();
    if (tid < 64) {
        float q0 = 0.f, q1 = 0.f;
        for (int i = 0; i < 16; i++) {
            float2 e = red[tid * 16 + i];
            q0 += e.x; q1 += e.y;
        }
        float mx = fmaxf(q0, q1);
        float a0 = __expf(q0 - mx), a1 = __expf(q1 - mx);
        float dn = a0 + a1;
        outp[(rowbase + tid) * 2] = a0 / dn;
        outp[(rowbase + tid) * 2 + 1] = a1 / dn;
    }
}

extern "C" void kernel_launch(void* const* d_in, const int* in_sizes, int n_in,
                              void* d_out, int out_size, void* d_ws, size_t ws_size,
                              hipStream_t stream)
{
    const float* feats0 = (const float*)d_in[0];
    const float* feats1 = (const float*)d_in[1];
    const float* t0_pw = (const float*)d_in[2];
    const float* t0_pb = (const float*)d_in[3];
    const float* t0_w2 = (const float*)d_in[4];
    const float* t0_b2 = (const float*)d_in[5];
    const float* t0_g  = (const float*)d_in[6];
    const float* t0_be = (const float*)d_in[7];
    const float* t1_pw = (const float*)d_in[8];
    const float* t1_pb = (const float*)d_in[9];
    const float* t1_w2 = (const float*)d_in[10];
    const float* t1_b2 = (const float*)d_in[11];
    const float* t1_g  = (const float*)d_in[12];
    const float* t1_be = (const float*)d_in[13];
    const float* r_vec = (const float*)d_in[14];
    const float* attn_user = (const float*)d_in[15];
    const float* attn_item = (const float*)d_in[16];
    const float* su_w1 = (const float*)d_in[17];
    const float* su_b1 = (const float*)d_in[18];
    const float* su_w2 = (const float*)d_in[19];
    const float* si_w1 = (const float*)d_in[20];
    const float* si_b1 = (const float*)d_in[21];
    const float* si_w2 = (const float*)d_in[22];
    const float* cw1 = (const float*)d_in[23];
    const float* cb1 = (const float*)d_in[24];
    const float* cw2 = (const float*)d_in[25];
    const int* idx0 = (const int*)d_in[26];
    const int* idx1 = (const int*)d_in[27];
    const int* emi_user = (const int*)d_in[28];
    const int* tgt_user = (const int*)d_in[29];
    const int* emi_item = (const int*)d_in[30];
    const int* tgt_item = (const int*)d_in[31];
    float* outp = (float*)d_out;

    // workspace layout (256B aligned)
    char* ws = (char*)d_ws;
    __hip_bfloat16* feat = (__hip_bfloat16*)(ws + 0);   // 5,120,000
    int*     cnt    = (int*)(ws + 5120000);             // 131,072
    int*     cur    = (int*)(ws + 5251072);             // 131,072 (contiguous with cnt for one memset)
    int*     cur32  = (int*)(ws + 5382144);             // 512
    int*     offs   = (int*)(ws + 5382656);             // 131,088 -> pad 131,328
    float*   s_acc  = (float*)(ws + 5513984);           // 256
    ushort4* binbuf = (ushort4*)(ws + 5514240);         // 6,400,000
    ushort4* nodes  = (ushort4*)(ws + 11914240);        // 6,400,000
    float*   ret_buf= (float*)(ws + 18314240);          // 8,388,608  (end ~26.7 MB)

    tower_kernel<<<dim3((NN0 + 63) / 64, 2), 256, 0, stream>>>(
        feats0, feats1, t0_pw, t1_pw, t0_pb, t1_pb, t0_w2, t1_w2,
        t0_b2, t1_b2, t0_g, t1_g, t0_be, t1_be, idx0, idx1, feat);

    hipMemsetAsync(cnt, 0, 2 * 4 * BBB * sizeof(int), stream);
    hist_kernel<<<dim3((EEE + 255) / 256, 4), 256, 0, stream>>>(tgt_user, tgt_item, cnt);
    scan_kernel<<<4, 256, 0, stream>>>(cnt, offs, cur32, s_acc);
    binA_kernel<<<dim3((EEE + CHUNK - 1) / CHUNK, 4), 256, 0, stream>>>(
        tgt_user, tgt_item, emi_user, emi_item, cur32, binbuf);
    binB_kernel<<<dim3(64, 4), 256, 0, stream>>>(offs, cur, binbuf, nodes);

    flash_mp<<<dim3(BBB / 4, 4), 256, 0, stream>>>(feat, nodes, offs, r_vec,
                                                   attn_user, attn_item, ret_buf);

    sem_kernel<<<dim3(BBB / 64, 4), 256, 0, stream>>>(ret_buf, su_w1, su_b1, su_w2,
                                                      si_w1, si_b1, si_w2, s_acc);
    final_kernel<<<BBB / 64, 256, 0, stream>>>(ret_buf, s_acc, cw1, cb1, cw2, outp);
}

// Round 8
// 367.540 us; speedup vs baseline: 1.1579x; 1.1579x over previous
//
#include <hip/hip_runtime.h>
#include <hip/hip_bf16.h>
#include <math.h>

// MAGNN link prediction forward — fp32 compute; feat table stored bf16.
#define NN0 20000
#define NN1 20000
#define NTOT 40000
#define FF0 512
#define HIDD 64
#define EEE 200000
#define BBB 8192
#define AVV 128
#define CHH 128

__device__ __forceinline__ float fast_tanh(float x) {
    float e2 = __expf(2.f * x);
    return 1.f - 2.f / (e2 + 1.f);
}

// ---------------- tower: Linear(512->64) + GELU + Linear(64->64) + residual + LN ----------------
// 32-row tiles, 256 threads, 2x4 register tile; simple load->barrier->compute chunks.
// 1250 blocks fill the 256-CU machine (~5 blocks/CU); 25KB LDS -> 6 blocks/CU cap.
__global__ __launch_bounds__(256) void tower_kernel(
    const float* __restrict__ x0, const float* __restrict__ x1,
    const float* __restrict__ pw0, const float* __restrict__ pw1,
    const float* __restrict__ pb0, const float* __restrict__ pb1,
    const float* __restrict__ w20, const float* __restrict__ w21,
    const float* __restrict__ b20, const float* __restrict__ b21,
    const float* __restrict__ g0, const float* __restrict__ g1,
    const float* __restrict__ be0, const float* __restrict__ be1,
    const int* __restrict__ idxa, const int* __restrict__ idxb,
    __hip_bfloat16* __restrict__ feat)
{
    int tw = blockIdx.y;
    const float* x  = tw ? x1 : x0;
    const float* pw = tw ? pw1 : pw0;
    const float* pb = tw ? pb1 : pb0;
    const float* w2 = tw ? w21 : w20;
    const float* b2 = tw ? b21 : b20;
    const float* g  = tw ? g1 : g0;
    const float* be = tw ? be1 : be0;
    const int* idx  = tw ? idxb : idxa;
    int nrows = NN0;

    __shared__ float xs[32][68];   // x k-chunk; reused for gelu(h), then y
    __shared__ float wsh[64][64];  // pw chunk, then w2
    int tid = threadIdx.x;
    int ct = tid & 15, rt = tid >> 4;   // rows 2rt..2rt+1, cols 4ct..4ct+3
    int row0 = blockIdx.x * 32;

    float acc[2][4];
#pragma unroll
    for (int j = 0; j < 2; j++)
#pragma unroll
        for (int i = 0; i < 4; i++) acc[j][i] = 0.f;

    for (int k0 = 0; k0 < FF0; k0 += 64) {
        // stage x tile 32 rows x 64 k (512 float4, 2/thread)
#pragma unroll
        for (int q = 0; q < 2; q++) {
            int li = tid + q * 256;
            int r = li >> 4, k4 = (li & 15) * 4;
            int gr = row0 + r;
            float4 v = (gr < nrows) ? *(const float4*)&x[(long)gr * FF0 + k0 + k4]
                                    : make_float4(0.f, 0.f, 0.f, 0.f);
            *(float4*)&xs[r][k4] = v;
        }
        // stage pw chunk 64 k x 64 col (1024 float4, 4/thread)
        const float4* pw4 = (const float4*)(pw + k0 * 64);
#pragma unroll
        for (int q = 0; q < 4; q++) {
            int li = tid + q * 256;
            float4 v = pw4[li];
            *(float4*)&wsh[li >> 4][(li & 15) * 4] = v;
        }
        __syncthreads();
        for (int k = 0; k < 64; k += 4) {
            float4 xv0 = *(const float4*)&xs[2 * rt][k];
            float4 xv1 = *(const float4*)&xs[2 * rt + 1][k];
#pragma unroll
            for (int kk = 0; kk < 4; kk++) {
                float4 wv = *(const float4*)&wsh[k + kk][4 * ct];
                float a0 = kk == 0 ? xv0.x : kk == 1 ? xv0.y : kk == 2 ? xv0.z : xv0.w;
                float a1 = kk == 0 ? xv1.x : kk == 1 ? xv1.y : kk == 2 ? xv1.z : xv1.w;
                acc[0][0] = fmaf(a0, wv.x, acc[0][0]);
                acc[0][1] = fmaf(a0, wv.y, acc[0][1]);
                acc[0][2] = fmaf(a0, wv.z, acc[0][2]);
                acc[0][3] = fmaf(a0, wv.w, acc[0][3]);
                acc[1][0] = fmaf(a1, wv.x, acc[1][0]);
                acc[1][1] = fmaf(a1, wv.y, acc[1][1]);
                acc[1][2] = fmaf(a1, wv.z, acc[1][2]);
                acc[1][3] = fmaf(a1, wv.w, acc[1][3]);
            }
        }
        __syncthreads();
    }

    // z = acc + pb; h = gelu(z) -> xs (reused); w2 -> wsh
    float4 pbv = *(const float4*)&pb[4 * ct];
    float z[2][4];
#pragma unroll
    for (int j = 0; j < 2; j++) {
        z[j][0] = acc[j][0] + pbv.x; z[j][1] = acc[j][1] + pbv.y;
        z[j][2] = acc[j][2] + pbv.z; z[j][3] = acc[j][3] + pbv.w;
        float4 hv;
        hv.x = 0.5f * z[j][0] * (1.f + erff(z[j][0] * 0.70710678118654752f));
        hv.y = 0.5f * z[j][1] * (1.f + erff(z[j][1] * 0.70710678118654752f));
        hv.z = 0.5f * z[j][2] * (1.f + erff(z[j][2] * 0.70710678118654752f));
        hv.w = 0.5f * z[j][3] * (1.f + erff(z[j][3] * 0.70710678118654752f));
        *(float4*)&xs[2 * rt + j][4 * ct] = hv;
    }
    const float4* w24 = (const float4*)w2;
#pragma unroll
    for (int q = 0; q < 4; q++) {
        int li = tid + q * 256;
        float4 v = w24[li];
        *(float4*)&wsh[li >> 4][(li & 15) * 4] = v;
    }
    __syncthreads();

    // GEMM2: y = h@w2 + b2 + z
    float4 b2v = *(const float4*)&b2[4 * ct];
    float acc2[2][4];
#pragma unroll
    for (int j = 0; j < 2; j++) {
        acc2[j][0] = z[j][0] + b2v.x; acc2[j][1] = z[j][1] + b2v.y;
        acc2[j][2] = z[j][2] + b2v.z; acc2[j][3] = z[j][3] + b2v.w;
    }
    for (int k = 0; k < 64; k += 4) {
        float4 xv0 = *(const float4*)&xs[2 * rt][k];
        float4 xv1 = *(const float4*)&xs[2 * rt + 1][k];
#pragma unroll
        for (int kk = 0; kk < 4; kk++) {
            float4 wv = *(const float4*)&wsh[k + kk][4 * ct];
            float a0 = kk == 0 ? xv0.x : kk == 1 ? xv0.y : kk == 2 ? xv0.z : xv0.w;
            float a1 = kk == 0 ? xv1.x : kk == 1 ? xv1.y : kk == 2 ? xv1.z : xv1.w;
            acc2[0][0] = fmaf(a0, wv.x, acc2[0][0]);
            acc2[0][1] = fmaf(a0, wv.y, acc2[0][1]);
            acc2[0][2] = fmaf(a0, wv.z, acc2[0][2]);
            acc2[0][3] = fmaf(a0, wv.w, acc2[0][3]);
            acc2[1][0] = fmaf(a1, wv.x, acc2[1][0]);
            acc2[1][1] = fmaf(a1, wv.y, acc2[1][1]);
            acc2[1][2] = fmaf(a1, wv.z, acc2[1][2]);
            acc2[1][3] = fmaf(a1, wv.w, acc2[1][3]);
        }
    }
    __syncthreads();
#pragma unroll
    for (int j = 0; j < 2; j++)
        *(float4*)&xs[2 * rt + j][4 * ct] = make_float4(acc2[j][0], acc2[j][1], acc2[j][2], acc2[j][3]);
    __syncthreads();

    // LayerNorm: lane = col, 4 waves x 8 rows
    int lane = tid & 63, wid = tid >> 6;
    float gc = g[lane], bec = be[lane];
    for (int rr = wid; rr < 32; rr += 4) {
        float y = xs[rr][lane];
        float mu = y;
        for (int off = 32; off; off >>= 1) mu += __shfl_xor(mu, off);
        mu *= (1.f / 64.f);
        float d = y - mu;
        float var = d * d;
        for (int off = 32; off; off >>= 1) var += __shfl_xor(var, off);
        var *= (1.f / 64.f);
        float o = d / sqrtf(var + 1e-5f) * gc + bec;
        int grow = row0 + rr;
        if (grow < nrows) feat[(long)idx[grow] * HIDD + lane] = __float2bfloat16(o);
    }
}

// ---------------- CSR build: hist -> scan -> binA (coarse) -> binB (exact) ----------------
__global__ void hist_kernel(const int* __restrict__ tgt_user, const int* __restrict__ tgt_item,
                            int* __restrict__ cnt)
{
    int combo = blockIdx.y;
    const int* tgt = (combo < 2 ? tgt_user : tgt_item) + (long)(combo & 1) * EEE;
    int i = blockIdx.x * 256 + threadIdx.x;
    if (i < EEE) atomicAdd(&cnt[combo * BBB + tgt[i]], 1);
}

__global__ __launch_bounds__(256) void scan_kernel(const int* __restrict__ cnt, int* __restrict__ offs,
                                                   int* __restrict__ cur32, float* __restrict__ s_acc)
{
    int pth = blockIdx.x;
    if (pth == 0 && threadIdx.x < 4) s_acc[threadIdx.x] = 0.f;
    const int* c = cnt + pth * BBB;
    int* o = offs + pth * (BBB + 1);
    __shared__ int part[256];
    int tid = threadIdx.x;
    int base = tid * 32;
    int local[32];
    int sum = 0;
    for (int j = 0; j < 32; j++) { local[j] = sum; sum += c[base + j]; }
    part[tid] = sum;
    __syncthreads();
    for (int d = 1; d < 256; d <<= 1) {
        int v = (tid >= d) ? part[tid - d] : 0;
        __syncthreads();
        part[tid] += v;
        __syncthreads();
    }
    int pre = (tid == 0) ? 0 : part[tid - 1];
    for (int j = 0; j < 32; j++) {
        int val = pre + local[j];
        o[base + j] = val;
        if (((base + j) & 255) == 0) cur32[pth * 32 + ((base + j) >> 8)] = val;
    }
    if (tid == 255) o[BBB] = pre + sum;
}

// pass A: bin instances into 32 coarse buckets (256 targets each), LDS-sorted, coalesced run writes
#define CHUNK 2048
__global__ __launch_bounds__(256) void binA_kernel(
    const int* __restrict__ tgt_user, const int* __restrict__ tgt_item,
    const int* __restrict__ emi_user, const int* __restrict__ emi_item,
    int* __restrict__ cur32, ushort4* __restrict__ binbuf)
{
    int combo = blockIdx.y;
    const int* tgt = (combo < 2 ? tgt_user : tgt_item) + (long)(combo & 1) * EEE;
    const int* emi = (combo < 2 ? emi_user : emi_item) + (long)(combo & 1) * EEE * 3;
    __shared__ ushort4 sbuf[CHUNK];
    __shared__ int lcnt[32], lofs[33], gbase[32], lcur[32];
    int tid = threadIdx.x;
    int base = blockIdx.x * CHUNK;
    if (tid < 32) { lcnt[tid] = 0; lcur[tid] = 0; }
    __syncthreads();
    ushort4 ent[8]; int bk[8];
#pragma unroll
    for (int ps = 0; ps < 8; ps++) {
        int i = base + ps * 256 + tid;
        if (i < EEE) {
            int t = tgt[i];
            ent[ps] = make_ushort4((unsigned short)emi[3 * i], (unsigned short)emi[3 * i + 1],
                                   (unsigned short)emi[3 * i + 2], (unsigned short)t);
            bk[ps] = t >> 8;
            atomicAdd(&lcnt[bk[ps]], 1);
        } else bk[ps] = -1;
    }
    __syncthreads();
    if (tid == 0) {
        int run = 0;
        for (int k = 0; k < 32; k++) { lofs[k] = run; run += lcnt[k]; }
        lofs[32] = run;
    }
    __syncthreads();
    if (tid < 32) gbase[tid] = atomicAdd(&cur32[combo * 32 + tid], lcnt[tid]);
    __syncthreads();
#pragma unroll
    for (int ps = 0; ps < 8; ps++) {
        if (bk[ps] >= 0) {
            int pos = lofs[bk[ps]] + atomicAdd(&lcur[bk[ps]], 1);
            sbuf[pos] = ent[ps];
        }
    }
    __syncthreads();
    int total = lofs[32];
    ushort4* dst = binbuf + (long)combo * EEE;
    for (int j = tid; j < total; j += 256) {
        ushort4 e = sbuf[j];
        int k = e.w >> 8;
        dst[gbase[k] + (j - lofs[k])] = e;
    }
}

// pass B: within each coarse bucket (contiguous ~50KB window), place entries at exact CSR position
__global__ __launch_bounds__(256) void binB_kernel(
    const int* __restrict__ offs, int* __restrict__ cur,
    const ushort4* __restrict__ binbuf, ushort4* __restrict__ nodes)
{
    int combo = blockIdx.y;
    int k = blockIdx.x >> 1, part = blockIdx.x & 1;
    const int* of = offs + combo * (BBB + 1);
    int rbeg = of[k << 8], rend = of[(k + 1) << 8];
    const ushort4* src = binbuf + (long)combo * EEE;
    ushort4* dst = nodes + (long)combo * EEE;
    int* cu = cur + combo * BBB;
    for (int j = rbeg + part * 256 + threadIdx.x; j < rend; j += 512) {
        ushort4 e = src[j];
        int t = e.w;
        int pos = of[t] + atomicAdd(&cu[t], 1);
        dst[pos] = e;
    }
}

// ---------------- flash metapath: gather + rotate + attention + online softmax + ELU ----------------
__global__ __launch_bounds__(256) void flash_mp(
    const __hip_bfloat16* __restrict__ feat, const ushort4* __restrict__ nodes,
    const int* __restrict__ offs, const float* __restrict__ r_vec,
    const float* __restrict__ attn_user, const float* __restrict__ attn_item,
    float* __restrict__ ret)
{
    int combo = blockIdx.y;
    int wid = threadIdx.x >> 6, lane = threadIdx.x & 63;
    int half = lane >> 5, p = lane & 31;
    int side = combo >> 1;
    const float* attn = (side == 0 ? attn_user : attn_item) + (combo & 1) * 64;
    const __hip_bfloat162* f2 = (const __hip_bfloat162*)feat;
    float2 rb = ((const float2*)r_vec)[p];
    float invn = 1.f / sqrtf(rb.x * rb.x + rb.y * rb.y);
    float rvx = rb.x * invn, rvy = rb.y * invn;
    if (side == 0) rvy = -rvy;
    float aRe = attn[2 * p], aIm = attn[2 * p + 1];
    int t = blockIdx.x * 4 + wid;
    int beg = offs[combo * (BBB + 1) + t], end = offs[combo * (BBB + 1) + t + 1];
    int n = end - beg;
    const ushort4* nd = nodes + (long)combo * EEE;

    float m = -3.4e38f, s = 0.f, Ox = 0.f, Oy = 0.f;

    __hip_bfloat162 c[8][3];
    ushort4 nq[8];
    if (n > 0) {
#pragma unroll
        for (int q = 0; q < 8; q++) {
            int j = beg + 2 * q + half; if (j >= end) j = end - 1;
            ushort4 a = nd[j];
            c[q][0] = f2[(int)a.x * 32 + p];
            c[q][1] = f2[(int)a.y * 32 + p];
            c[q][2] = f2[(int)a.z * 32 + p];
        }
#pragma unroll
        for (int q = 0; q < 8; q++) {
            int j = beg + 16 + 2 * q + half; if (j >= end) j = end - 1;
            nq[q] = nd[j];
        }
    }
    for (int it = 0; it < n; it += 16) {
        float2 u[8][3];
#pragma unroll
        for (int q = 0; q < 8; q++)
#pragma unroll
            for (int r = 0; r < 3; r++)
                u[q][r] = __bfloat1622float2(c[q][r]);
        if (it + 16 < n) {
#pragma unroll
            for (int q = 0; q < 8; q++) {
                c[q][0] = f2[(int)nq[q].x * 32 + p];
                c[q][1] = f2[(int)nq[q].y * 32 + p];
                c[q][2] = f2[(int)nq[q].z * 32 + p];
            }
#pragma unroll
            for (int q = 0; q < 8; q++) {
                int j = beg + it + 32 + 2 * q + half; if (j >= end) j = end - 1;
                nq[q] = nd[j];
            }
        }
        float re[8], im[8], e[8];
#pragma unroll
        for (int q = 0; q < 8; q++) {
            re[q] = (u[q][0].x + u[q][2].x + u[q][1].x * rvx - u[q][1].y * rvy) * (1.f / 3.f);
            im[q] = (u[q][0].y + u[q][2].y + u[q][1].x * rvy + u[q][1].y * rvx) * (1.f / 3.f);
            float pa = re[q] * aRe + im[q] * aIm;
            pa += __shfl_xor(pa, 1);
            pa += __shfl_xor(pa, 2);
            float ev = pa > 0.f ? pa : 0.01f * pa;       // leaky_relu
            if (it + 2 * q + half >= n) ev = -3.4e38f;
            e[q] = ev;
        }
        float mx = e[0];
#pragma unroll
        for (int q = 1; q < 8; q++) mx = fmaxf(mx, e[q]);
        float mn = fmaxf(m, fmaxf(mx, __shfl_xor(mx, 32)));
        float alpha = __expf(m - mn);
        float wl = 0.f, ax = 0.f, ay = 0.f;
#pragma unroll
        for (int q = 0; q < 8; q++) {
            float w = __expf(e[q] - mn);
            wl += w; ax = fmaf(w, re[q], ax); ay = fmaf(w, im[q], ay);
        }
        s = s * alpha + wl + __shfl_xor(wl, 32);
        Ox = Ox * alpha + ax;
        Oy = Oy * alpha + ay;
        m = mn;
    }
    float sx = __shfl_xor(Ox, 32), sy = __shfl_xor(Oy, 32);
    float inv = 1.f / (s + 1e-9f);
    float vx = (Ox + sx) * inv, vy = (Oy + sy) * inv;
    vx = vx > 0.f ? vx : __expf(vx) - 1.f;   // ELU
    vy = vy > 0.f ? vy : __expf(vy) - 1.f;
    if (half == 0)
        ((float2*)ret)[((long)combo * BBB + t) * 32 + p] = make_float2(vx, vy);
}

// ---------------- semantic score GEMM: s_acc[combo] = sum_b tanh(ret_b @ w1 + b1) @ w2 ----------------
__global__ __launch_bounds__(256) void sem_kernel(
    const float* __restrict__ ret,
    const float* __restrict__ su_w1, const float* __restrict__ su_b1, const float* __restrict__ su_w2,
    const float* __restrict__ si_w1, const float* __restrict__ si_b1, const float* __restrict__ si_w2,
    float* __restrict__ s_acc)
{
    int combo = blockIdx.y;
    int side = combo >> 1;
    const float* w1 = side ? si_w1 : su_w1;
    const float* b1 = side ? si_b1 : su_b1;
    const float* w2 = side ? si_w2 : su_w2;
    __shared__ float vs[64][68];
    __shared__ float w1s[64][128];
    int tid = threadIdx.x;
    int rowbase = blockIdx.x * 64;
    const float4* r4 = (const float4*)ret;
    for (int li = tid; li < 1024; li += 256) {
        int r = li >> 4, c4 = li & 15;
        float4 v = r4[((long)combo * BBB + rowbase + r) * 16 + c4];
        *(float4*)&vs[r][c4 * 4] = v;
    }
    const float4* w14 = (const float4*)w1;
    for (int li = tid; li < 2048; li += 256) {
        float4 v = w14[li];
        *(float4*)&w1s[li >> 5][(li & 31) * 4] = v;
    }
    __syncthreads();
    int ct = tid & 15, rt = tid >> 4;
    float acc[4][8];
#pragma unroll
    for (int cc = 0; cc < 8; cc++) {
        float b = b1[8 * ct + cc];
#pragma unroll
        for (int j = 0; j < 4; j++) acc[j][cc] = b;
    }
    for (int k = 0; k < 64; k += 4) {
        float4 xv[4];
#pragma unroll
        for (int j = 0; j < 4; j++) xv[j] = *(const float4*)&vs[4 * rt + j][k];
#pragma unroll
        for (int kk = 0; kk < 4; kk++) {
            float4 wv0 = *(const float4*)&w1s[k + kk][8 * ct];
            float4 wv1 = *(const float4*)&w1s[k + kk][8 * ct + 4];
#pragma unroll
            for (int j = 0; j < 4; j++) {
                float xx = kk == 0 ? xv[j].x : kk == 1 ? xv[j].y : kk == 2 ? xv[j].z : xv[j].w;
                acc[j][0] = fmaf(xx, wv0.x, acc[j][0]);
                acc[j][1] = fmaf(xx, wv0.y, acc[j][1]);
                acc[j][2] = fmaf(xx, wv0.z, acc[j][2]);
                acc[j][3] = fmaf(xx, wv0.w, acc[j][3]);
                acc[j][4] = fmaf(xx, wv1.x, acc[j][4]);
                acc[j][5] = fmaf(xx, wv1.y, acc[j][5]);
                acc[j][6] = fmaf(xx, wv1.z, acc[j][6]);
                acc[j][7] = fmaf(xx, wv1.w, acc[j][7]);
            }
        }
    }
    float tot = 0.f;
#pragma unroll
    for (int cc = 0; cc < 8; cc++) {
        float w2v = w2[8 * ct + cc];
#pragma unroll
        for (int j = 0; j < 4; j++) tot += fast_tanh(acc[j][cc]) * w2v;
    }
    for (int off = 32; off; off >>= 1) tot += __shfl_xor(tot, off);
    __shared__ float red[4];
    int lane = tid & 63, wid = tid >> 6;
    if (lane == 0) red[wid] = tot;
    __syncthreads();
    if (tid == 0) atomicAdd(&s_acc[combo], red[0] + red[1] + red[2] + red[3]);
}

// ---------------- final product MLP + softmax (beta inline, GEMM-tiled) ----------------
__global__ __launch_bounds__(256) void final_kernel(
    const float* __restrict__ ret, const float* __restrict__ s_acc,
    const float* __restrict__ cw1, const float* __restrict__ cb1, const float* __restrict__ cw2,
    float* __restrict__ outp)
{
    float s0 = s_acc[0] * (1.f / BBB), s1 = s_acc[1] * (1.f / BBB);
    float s2 = s_acc[2] * (1.f / BBB), s3 = s_acc[3] * (1.f / BBB);
    float mu = fmaxf(s0, s1);
    float e0 = __expf(s0 - mu), e1 = __expf(s1 - mu);
    float bu0 = e0 / (e0 + e1), bu1 = e1 / (e0 + e1);
    float mi = fmaxf(s2, s3);
    float f0 = __expf(s2 - mi), f1 = __expf(s3 - mi);
    float bi0 = f0 / (f0 + f1), bi1 = f1 / (f0 + f1);

    __shared__ float xsld[64][68];
    __shared__ float w1s[64][128];
    int tid = threadIdx.x;
    int rowbase = blockIdx.x * 64;
    const float4* r4 = (const float4*)ret;
    for (int li = tid; li < 1024; li += 256) {
        int r = li >> 4, c4 = li & 15;
        float4 a = r4[((long)0 * BBB + rowbase + r) * 16 + c4];
        float4 b = r4[((long)1 * BBB + rowbase + r) * 16 + c4];
        float4 cc = r4[((long)2 * BBB + rowbase + r) * 16 + c4];
        float4 d = r4[((long)3 * BBB + rowbase + r) * 16 + c4];
        float4 xv;
        xv.x = (bu0 * a.x + bu1 * b.x) * (bi0 * cc.x + bi1 * d.x);
        xv.y = (bu0 * a.y + bu1 * b.y) * (bi0 * cc.y + bi1 * d.y);
        xv.z = (bu0 * a.z + bu1 * b.z) * (bi0 * cc.z + bi1 * d.z);
        xv.w = (bu0 * a.w + bu1 * b.w) * (bi0 * cc.w + bi1 * d.w);
        *(float4*)&xsld[r][c4 * 4] = xv;
    }
    const float4* w14 = (const float4*)cw1;
    for (int li = tid; li < 2048; li += 256) {
        float4 v = w14[li];
        *(float4*)&w1s[li >> 5][(li & 31) * 4] = v;
    }
    __syncthreads();
    int ct = tid & 15, rt = tid >> 4;
    float acc[4][8];
#pragma unroll
    for (int cc = 0; cc < 8; cc++) {
        float b = cb1[8 * ct + cc];
#pragma unroll
        for (int j = 0; j < 4; j++) acc[j][cc] = b;
    }
    for (int k = 0; k < 64; k += 4) {
        float4 xv[4];
#pragma unroll
        for (int j = 0; j < 4; j++) xv[j] = *(const float4*)&xsld[4 * rt + j][k];
#pragma unroll
        for (int kk = 0; kk < 4; kk++) {
            float4 wv0 = *(const float4*)&w1s[k + kk][8 * ct];
            float4 wv1 = *(const float4*)&w1s[k + kk][8 * ct + 4];
#pragma unroll
            for (int j = 0; j < 4; j++) {
                float xx = kk == 0 ? xv[j].x : kk == 1 ? xv[j].y : kk == 2 ? xv[j].z : xv[j].w;
                acc[j][0] = fmaf(xx, wv0.x, acc[j][0]);
                acc[j][1] = fmaf(xx, wv0.y, acc[j][1]);
                acc[j][2] = fmaf(xx, wv0.z, acc[j][2]);
                acc[j][3] = fmaf(xx, wv0.w, acc[j][3]);
                acc[j][4] = fmaf(xx, wv1.x, acc[j][4]);
                acc[j][5] = fmaf(xx, wv1.y, acc[j][5]);
                acc[j][6] = fmaf(xx, wv1.z, acc[j][6]);
                acc[j][7] = fmaf(xx, wv1.w, acc[j][7]);
            }
        }
    }
    float pp0[4], pp1[4];
#pragma unroll
    for (int j = 0; j < 4; j++) { pp0[j] = 0.f; pp1[j] = 0.f; }
#pragma unroll
    for (int cc = 0; cc < 8; cc++) {
        int col = 8 * ct + cc;
        float c0 = cw2[col * 2], c1 = cw2[col * 2 + 1];
#pragma unroll
        for (int j = 0; j < 4; j++) {
            float h = fmaxf(acc[j][cc], 0.f);
            pp0[j] = fmaf(h, c0, pp0[j]);
            pp1[j] = fmaf(h, c1, pp1[j]);
        }
    }
    __syncthreads();
    float2* red = (float2*)xsld;
#pragma unroll
    for (int j = 0; j < 4; j++)
        red[(4 * rt + j) * 16 + ct] = make_float2(pp0[j], pp1[j]);
    __syncthreads();
    if (tid < 64) {
        float q0 = 0.f, q1 = 0.f;
        for (int i = 0; i < 16; i++) {
            float2 e = red[tid * 16 + i];
            q0 += e.x; q1 += e.y;
        }
        float mx = fmaxf(q0, q1);
        float a0 = __expf(q0 - mx), a1 = __expf(q1 - mx);
        float dn = a0 + a1;
        outp[(rowbase + tid) * 2] = a0 / dn;
        outp[(rowbase + tid) * 2 + 1] = a1 / dn;
    }
}

extern "C" void kernel_launch(void* const* d_in, const int* in_sizes, int n_in,
                              void* d_out, int out_size, void* d_ws, size_t ws_size,
                              hipStream_t stream)
{
    const float* feats0 = (const float*)d_in[0];
    const float* feats1 = (const float*)d_in[1];
    const float* t0_pw = (const float*)d_in[2];
    const float* t0_pb = (const float*)d_in[3];
    const float* t0_w2 = (const float*)d_in[4];
    const float* t0_b2 = (const float*)d_in[5];
    const float* t0_g  = (const float*)d_in[6];
    const float* t0_be = (const float*)d_in[7];
    const float* t1_pw = (const float*)d_in[8];
    const float* t1_pb = (const float*)d_in[9];
    const float* t1_w2 = (const float*)d_in[10];
    const float* t1_b2 = (const float*)d_in[11];
    const float* t1_g  = (const float*)d_in[12];
    const float* t1_be = (const float*)d_in[13];
    const float* r_vec = (const float*)d_in[14];
    const float* attn_user = (const float*)d_in[15];
    const float* attn_item = (const float*)d_in[16];
    const float* su_w1 = (const float*)d_in[17];
    const float* su_b1 = (const float*)d_in[18];
    const float* su_w2 = (const float*)d_in[19];
    const float* si_w1 = (const float*)d_in[20];
    const float* si_b1 = (const float*)d_in[21];
    const float* si_w2 = (const float*)d_in[22];
    const float* cw1 = (const float*)d_in[23];
    const float* cb1 = (const float*)d_in[24];
    const float* cw2 = (const float*)d_in[25];
    const int* idx0 = (const int*)d_in[26];
    const int* idx1 = (const int*)d_in[27];
    const int* emi_user = (const int*)d_in[28];
    const int* tgt_user = (const int*)d_in[29];
    const int* emi_item = (const int*)d_in[30];
    const int* tgt_item = (const int*)d_in[31];
    float* outp = (float*)d_out;

    // workspace layout (256B aligned)
    char* ws = (char*)d_ws;
    __hip_bfloat16* feat = (__hip_bfloat16*)(ws + 0);   // 5,120,000
    int*     cnt    = (int*)(ws + 5120000);             // 131,072
    int*     cur    = (int*)(ws + 5251072);             // 131,072 (contiguous with cnt for one memset)
    int*     cur32  = (int*)(ws + 5382144);             // 512
    int*     offs   = (int*)(ws + 5382656);             // 131,088 -> pad 131,328
    float*   s_acc  = (float*)(ws + 5513984);           // 256
    ushort4* binbuf = (ushort4*)(ws + 5514240);         // 6,400,000
    ushort4* nodes  = (ushort4*)(ws + 11914240);        // 6,400,000
    float*   ret_buf= (float*)(ws + 18314240);          // 8,388,608  (end ~26.7 MB)

    tower_kernel<<<dim3(NN0 / 32, 2), 256, 0, stream>>>(
        feats0, feats1, t0_pw, t1_pw, t0_pb, t1_pb, t0_w2, t1_w2,
        t0_b2, t1_b2, t0_g, t1_g, t0_be, t1_be, idx0, idx1, feat);

    hipMemsetAsync(cnt, 0, 2 * 4 * BBB * sizeof(int), stream);
    hist_kernel<<<dim3((EEE + 255) / 256, 4), 256, 0, stream>>>(tgt_user, tgt_item, cnt);
    scan_kernel<<<4, 256, 0, stream>>>(cnt, offs, cur32, s_acc);
    binA_kernel<<<dim3((EEE + CHUNK - 1) / CHUNK, 4), 256, 0, stream>>>(
        tgt_user, tgt_item, emi_user, emi_item, cur32, binbuf);
    binB_kernel<<<dim3(64, 4), 256, 0, stream>>>(offs, cur, binbuf, nodes);

    flash_mp<<<dim3(BBB / 4, 4), 256, 0, stream>>>(feat, nodes, offs, r_vec,
                                                   attn_user, attn_item, ret_buf);

    sem_kernel<<<dim3(BBB / 64, 4), 256, 0, stream>>>(ret_buf, su_w1, su_b1, su_w2,
                                                      si_w1, si_b1, si_w2, s_acc);
    final_kernel<<<BBB / 64, 256, 0, stream>>>(ret_buf, s_acc, cw1, cb1, cw2, outp);
}